// Round 1
// baseline (684.365 us; speedup 1.0000x reference)
//
#include <hip/hip_runtime.h>
#include <hip/hip_bf16.h>
#include <math.h>

#define E_EXPERTS 8
#define D_DIM 768
#define H_DIM 3072
#define N_TOK 8192          // B*T = 4*2048
#define SLOTS (2 * N_TOK)

typedef unsigned short ushort_t;
typedef __attribute__((ext_vector_type(8))) __bf16 bf16x8;
typedef __attribute__((ext_vector_type(4))) float f32x4;
typedef __attribute__((ext_vector_type(8))) unsigned short u16x8;

__device__ __forceinline__ unsigned short f2bf(float f) {
    unsigned int u = __float_as_uint(f);
    unsigned int r = (u + 0x7FFFu + ((u >> 16) & 1u)) >> 16;
    return (unsigned short)r;
}

// ---------------- prep kernels ----------------

__global__ void convert_x_kernel(const float* __restrict__ x, ushort_t* __restrict__ xb, int nquads) {
    int i = blockIdx.x * blockDim.x + threadIdx.x;
    int stride = gridDim.x * blockDim.x;
    for (int idx = i; idx < nquads; idx += stride) {
        float4 v = ((const float4*)x)[idx];
        ushort4 o;
        o.x = f2bf(v.x); o.y = f2bf(v.y); o.z = f2bf(v.z); o.w = f2bf(v.w);
        ((ushort4*)xb)[idx] = o;
    }
}

// dst[e][c][r] = bf16(src[e][r][c]);  R,C multiples of 32
__global__ void transpose_conv_kernel(const float* __restrict__ src, ushort_t* __restrict__ dst,
                                      int R, int C) {
    __shared__ float tile[32][33];
    int e = blockIdx.z;
    const float* S = src + (size_t)e * R * C;
    ushort_t* Dp = dst + (size_t)e * R * C;
    int c0 = blockIdx.x * 32, r0 = blockIdx.y * 32;
    int tx = threadIdx.x & 31, ty = threadIdx.x >> 5;  // 32 x 8
#pragma unroll
    for (int p = 0; p < 4; p++)
        tile[ty + 8 * p][tx] = S[(size_t)(r0 + ty + 8 * p) * C + c0 + tx];
    __syncthreads();
#pragma unroll
    for (int p = 0; p < 4; p++)
        Dp[(size_t)(c0 + ty + 8 * p) * R + r0 + tx] = f2bf(tile[tx][ty + 8 * p]);
}

// ---------------- routing ----------------

__global__ void gate_kernel(const float* __restrict__ x, const float* __restrict__ Wg,
                            const float* __restrict__ bg, int* __restrict__ top_idx,
                            float* __restrict__ top_w, int* __restrict__ counts) {
    int w = threadIdx.x >> 6, lane = threadIdx.x & 63;
    int t = blockIdx.x * 4 + w;
    if (t >= N_TOK) return;
    const float* xr = x + (size_t)t * D_DIM;
    float xs[12];
#pragma unroll
    for (int j = 0; j < 12; j++) xs[j] = xr[lane + 64 * j];
    float pr[8];
#pragma unroll
    for (int ee = 0; ee < 8; ee++) {
        const float* wr = Wg + ee * D_DIM;
        float p = 0.f;
#pragma unroll
        for (int j = 0; j < 12; j++) p += xs[j] * wr[lane + 64 * j];
#pragma unroll
        for (int o = 32; o > 0; o >>= 1) p += __shfl_xor(p, o);
        pr[ee] = p + bg[ee];
    }
    float mx = pr[0];
#pragma unroll
    for (int ee = 1; ee < 8; ee++) mx = fmaxf(mx, pr[ee]);
    float s = 0.f;
#pragma unroll
    for (int ee = 0; ee < 8; ee++) { pr[ee] = expf(pr[ee] - mx); s += pr[ee]; }
    float inv = 1.f / s;
#pragma unroll
    for (int ee = 0; ee < 8; ee++) pr[ee] *= inv;
    int i0 = 0;
#pragma unroll
    for (int ee = 1; ee < 8; ee++) if (pr[ee] > pr[i0]) i0 = ee;
    int i1 = -1;
#pragma unroll
    for (int ee = 0; ee < 8; ee++) {
        if (ee == i0) continue;
        if (i1 < 0 || pr[ee] > pr[i1]) i1 = ee;
    }
    if (lane == 0) {
        top_idx[2 * t] = i0;
        top_idx[2 * t + 1] = i1;
        top_w[2 * t] = pr[i0];
        top_w[2 * t + 1] = pr[i1];
        atomicAdd(&counts[i0], 1);
        atomicAdd(&counts[i1], 1);
    }
}

__global__ void scan_kernel(const int* __restrict__ counts, int* __restrict__ offsets,
                            int* __restrict__ cursors) {
    if (threadIdx.x == 0) {
        int acc = 0;
        for (int e = 0; e < E_EXPERTS; e++) { offsets[e] = acc; acc += counts[e]; }
    }
    if (threadIdx.x < E_EXPERTS) cursors[threadIdx.x] = 0;
}

__global__ void scatter_kernel(const int* __restrict__ top_idx, const float* __restrict__ top_w,
                               const int* __restrict__ offsets, int* __restrict__ cursors,
                               int* __restrict__ perm, float* __restrict__ wgt) {
    int t = blockIdx.x * blockDim.x + threadIdx.x;
    if (t >= N_TOK) return;
#pragma unroll
    for (int sl = 0; sl < 2; sl++) {
        int ee = top_idx[2 * t + sl];
        int p = atomicAdd(&cursors[ee], 1);
        int s = offsets[ee] + p;
        perm[s] = t;
        wgt[s] = top_w[2 * t + sl];
    }
}

// ---------------- expert GEMMs ----------------
// MODE 0: A = xb gathered via perm, B = W1T[e] [3072][768], epilogue GELU -> Hout bf16
// MODE 1: A = Hb contiguous slots,  B = W2T[e] [768][3072], epilogue weighted atomic -> Out f32
template <int MODE>
__global__ __launch_bounds__(256, 2) void moe_gemm_kernel(
    const ushort_t* __restrict__ A, const ushort_t* __restrict__ BT,
    const float* __restrict__ bias, const int* __restrict__ offsets,
    const int* __restrict__ counts, const int* __restrict__ perm,
    const float* __restrict__ wgt, ushort_t* __restrict__ Hout, float* __restrict__ Out) {
    constexpr int K = (MODE == 0) ? D_DIM : H_DIM;
    constexpr int N = (MODE == 0) ? H_DIM : D_DIM;

    const int e = blockIdx.z;
    const int ne = counts[e];
    const int m0 = blockIdx.y * 128;
    if (m0 >= ne) return;
    const int n0 = blockIdx.x * 128;
    const int base = offsets[e];

    const ushort_t* Bt = BT + (size_t)e * ((size_t)N * K);

    __shared__ alignas(16) ushort_t As[128 * 32];
    __shared__ alignas(16) ushort_t Bs[128 * 32];

    const int tid = threadIdx.x;
    const int lane = tid & 63;
    const int w = tid >> 6;
    const int wm = w >> 1, wn = w & 1;

    // staging: 512 segments of 16B per tile (128 rows x 4 segs); thread -> segs {tid, tid+256}
    int arow[2], acol[2];
    const ushort_t* aptr[2];
    const ushort_t* bptr[2];
#pragma unroll
    for (int i = 0; i < 2; i++) {
        int s = tid + i * 256;
        int row = s >> 2;
        int c8 = (s & 3) * 8;
        int rclamp = min(m0 + row, ne - 1);
        size_t arow_g;
        if (MODE == 0)
            arow_g = (size_t)perm[base + rclamp] * K;
        else
            arow_g = (size_t)(base + rclamp) * K;
        aptr[i] = A + arow_g + c8;
        bptr[i] = Bt + (size_t)(n0 + row) * K + c8;
        arow[i] = row;
        acol[i] = c8;
    }

    f32x4 acc[4][4];
#pragma unroll
    for (int i = 0; i < 4; i++)
#pragma unroll
        for (int j = 0; j < 4; j++) acc[i][j] = (f32x4){0.f, 0.f, 0.f, 0.f};

    u16x8 pa[2], pb[2];
#pragma unroll
    for (int i = 0; i < 2; i++) {
        pa[i] = *(const u16x8*)(aptr[i]);
        pb[i] = *(const u16x8*)(bptr[i]);
    }

    const int lr = lane & 15;
    const int lk = (lane >> 4) * 8;
    constexpr int KSTEPS = K / 32;

    for (int kt = 0; kt < KSTEPS; kt++) {
#pragma unroll
        for (int i = 0; i < 2; i++) {
            *(u16x8*)&As[arow[i] * 32 + acol[i]] = pa[i];
            *(u16x8*)&Bs[arow[i] * 32 + acol[i]] = pb[i];
        }
        __syncthreads();
        if (kt + 1 < KSTEPS) {
#pragma unroll
            for (int i = 0; i < 2; i++) {
                pa[i] = *(const u16x8*)(aptr[i] + (kt + 1) * 32);
                pb[i] = *(const u16x8*)(bptr[i] + (kt + 1) * 32);
            }
        }
        bf16x8 af[4], bfr[4];
#pragma unroll
        for (int f = 0; f < 4; f++) {
            af[f] = *(const bf16x8*)&As[(wm * 64 + f * 16 + lr) * 32 + lk];
            bfr[f] = *(const bf16x8*)&Bs[(wn * 64 + f * 16 + lr) * 32 + lk];
        }
#pragma unroll
        for (int i = 0; i < 4; i++)
#pragma unroll
            for (int j = 0; j < 4; j++)
                acc[i][j] = __builtin_amdgcn_mfma_f32_16x16x32_bf16(af[i], bfr[j], acc[i][j], 0, 0, 0);
        __syncthreads();
    }

    const int r0 = (lane >> 4) * 4;
#pragma unroll
    for (int fm = 0; fm < 4; fm++) {
#pragma unroll
        for (int fn = 0; fn < 4; fn++) {
            int cn = n0 + wn * 64 + fn * 16 + lr;
            float bi = bias[e * N + cn];
            f32x4 v = acc[fm][fn];
#pragma unroll
            for (int rg = 0; rg < 4; rg++) {
                int rm = m0 + wm * 64 + fm * 16 + r0 + rg;
                if (rm < ne) {
                    if (MODE == 0) {
                        float xv = v[rg] + bi;
                        float g = 0.5f * xv * (1.0f + erff(xv * 0.70710678118654752f));
                        Hout[(size_t)(base + rm) * H_DIM + cn] = f2bf(g);
                    } else {
                        int s = base + rm;
                        int tok = perm[s];
                        float wv = wgt[s];
                        unsafeAtomicAdd(&Out[(size_t)tok * D_DIM + cn], wv * (v[rg] + bi));
                    }
                }
            }
        }
    }
}

// ---------------- launch ----------------

extern "C" void kernel_launch(void* const* d_in, const int* in_sizes, int n_in,
                              void* d_out, int out_size, void* d_ws, size_t ws_size,
                              hipStream_t stream) {
    const float* x  = (const float*)d_in[0];
    const float* Wg = (const float*)d_in[1];
    const float* bg = (const float*)d_in[2];
    const float* W1 = (const float*)d_in[3];
    const float* b1 = (const float*)d_in[4];
    const float* W2 = (const float*)d_in[5];
    const float* b2 = (const float*)d_in[6];
    float* out = (float*)d_out;

    char* p = (char*)d_ws;
    ushort_t* xb  = (ushort_t*)p; p += (size_t)N_TOK * D_DIM * 2;
    ushort_t* W1T = (ushort_t*)p; p += (size_t)E_EXPERTS * H_DIM * D_DIM * 2;
    ushort_t* W2T = (ushort_t*)p; p += (size_t)E_EXPERTS * D_DIM * H_DIM * 2;
    ushort_t* Hb  = (ushort_t*)p; p += (size_t)SLOTS * H_DIM * 2;
    int*   top_idx = (int*)p;   p += (size_t)N_TOK * 2 * 4;
    float* top_w   = (float*)p; p += (size_t)N_TOK * 2 * 4;
    int*   perm    = (int*)p;   p += (size_t)SLOTS * 4;
    float* wgt     = (float*)p; p += (size_t)SLOTS * 4;
    int*   counts  = (int*)p;   p += 64;
    int*   offsets = (int*)p;   p += 64;
    int*   cursors = (int*)p;   p += 64;

    hipMemsetAsync(d_out, 0, (size_t)out_size * sizeof(float), stream);
    hipMemsetAsync(counts, 0, 64, stream);

    convert_x_kernel<<<1024, 256, 0, stream>>>(x, xb, N_TOK * D_DIM / 4);
    transpose_conv_kernel<<<dim3(H_DIM / 32, D_DIM / 32, E_EXPERTS), 256, 0, stream>>>(W1, W1T, D_DIM, H_DIM);
    transpose_conv_kernel<<<dim3(D_DIM / 32, H_DIM / 32, E_EXPERTS), 256, 0, stream>>>(W2, W2T, H_DIM, D_DIM);
    gate_kernel<<<N_TOK / 4, 256, 0, stream>>>(x, Wg, bg, top_idx, top_w, counts);
    scan_kernel<<<1, 64, 0, stream>>>(counts, offsets, cursors);
    scatter_kernel<<<N_TOK / 256, 256, 0, stream>>>(top_idx, top_w, offsets, cursors, perm, wgt);
    moe_gemm_kernel<0><<<dim3(H_DIM / 128, 64, E_EXPERTS), 256, 0, stream>>>(
        xb, W1T, b1, offsets, counts, perm, wgt, Hb, nullptr);
    moe_gemm_kernel<1><<<dim3(D_DIM / 128, 64, E_EXPERTS), 256, 0, stream>>>(
        Hb, W2T, b2, offsets, counts, perm, wgt, nullptr, out);
}

// Round 2
// 671.732 us; speedup vs baseline: 1.0188x; 1.0188x over previous
//
#include <hip/hip_runtime.h>
#include <hip/hip_bf16.h>
#include <math.h>

#define E_EXPERTS 8
#define D_DIM 768
#define H_DIM 3072
#define N_TOK 8192          // B*T = 4*2048
#define SLOTS (2 * N_TOK)

typedef unsigned short ushort_t;
typedef __attribute__((ext_vector_type(8))) __bf16 bf16x8;
typedef __attribute__((ext_vector_type(4))) float f32x4;

__device__ __forceinline__ unsigned short f2bf(float f) {
    unsigned int u = __float_as_uint(f);
    unsigned int r = (u + 0x7FFFu + ((u >> 16) & 1u)) >> 16;
    return (unsigned short)r;
}

// async 16B global -> LDS (wave-uniform LDS base + lane*16; global addr per-lane)
__device__ __forceinline__ void gload_lds16(const void* g, void* l) {
    __builtin_amdgcn_global_load_lds(
        (const __attribute__((address_space(1))) unsigned int*)g,
        (__attribute__((address_space(3))) unsigned int*)l, 16, 0, 0);
}

// ---------------- prep kernels ----------------

// dst[e][c][r] = bf16(src[e][r][c]);  R,C multiples of 64
__global__ void transpose_conv_kernel(const float* __restrict__ src, ushort_t* __restrict__ dst,
                                      int R, int C) {
    __shared__ float tile[64][65];
    int e = blockIdx.z;
    const float* S = src + (size_t)e * R * C;
    ushort_t* Dp = dst + (size_t)e * R * C;
    int c0 = blockIdx.x * 64, r0 = blockIdx.y * 64;
    // load: 16 threads x 4 float4 cover one row of 64 floats; 16 rows per pass
    int tx = threadIdx.x & 15, ty = threadIdx.x >> 4;  // 16 x 16
#pragma unroll
    for (int p = 0; p < 4; p++) {
        float4 v = *(const float4*)&S[(size_t)(r0 + ty + 16 * p) * C + c0 + tx * 4];
        tile[ty + 16 * p][tx * 4 + 0] = v.x;
        tile[ty + 16 * p][tx * 4 + 1] = v.y;
        tile[ty + 16 * p][tx * 4 + 2] = v.z;
        tile[ty + 16 * p][tx * 4 + 3] = v.w;
    }
    __syncthreads();
    // store: dst row = c0+cc (length-64 run of r), ushort4 per thread
#pragma unroll
    for (int p = 0; p < 4; p++) {
        int cc = ty + 16 * p;
        int rr = tx * 4;
        ushort4 o;
        o.x = f2bf(tile[rr + 0][cc]);
        o.y = f2bf(tile[rr + 1][cc]);
        o.z = f2bf(tile[rr + 2][cc]);
        o.w = f2bf(tile[rr + 3][cc]);
        *(ushort4*)&Dp[(size_t)(c0 + cc) * R + r0 + rr] = o;
    }
}

// ---------------- routing (fused with x -> bf16 conversion) ----------------

__global__ void gate_kernel(const float* __restrict__ x, const float* __restrict__ Wg,
                            const float* __restrict__ bg, ushort_t* __restrict__ xb,
                            int* __restrict__ top_idx, float* __restrict__ top_w,
                            int* __restrict__ counts) {
    int w = threadIdx.x >> 6, lane = threadIdx.x & 63;
    int t = blockIdx.x * 4 + w;
    if (t >= N_TOK) return;
    const float* xr = x + (size_t)t * D_DIM;
    float xs[12];
#pragma unroll
    for (int j = 0; j < 12; j++) xs[j] = xr[lane + 64 * j];
    // fused conversion
#pragma unroll
    for (int j = 0; j < 12; j++) xb[(size_t)t * D_DIM + lane + 64 * j] = f2bf(xs[j]);
    float pr[8];
#pragma unroll
    for (int ee = 0; ee < 8; ee++) {
        const float* wr = Wg + ee * D_DIM;
        float p = 0.f;
#pragma unroll
        for (int j = 0; j < 12; j++) p += xs[j] * wr[lane + 64 * j];
#pragma unroll
        for (int o = 32; o > 0; o >>= 1) p += __shfl_xor(p, o);
        pr[ee] = p + bg[ee];
    }
    float mx = pr[0];
#pragma unroll
    for (int ee = 1; ee < 8; ee++) mx = fmaxf(mx, pr[ee]);
    float s = 0.f;
#pragma unroll
    for (int ee = 0; ee < 8; ee++) { pr[ee] = expf(pr[ee] - mx); s += pr[ee]; }
    float inv = 1.f / s;
#pragma unroll
    for (int ee = 0; ee < 8; ee++) pr[ee] *= inv;
    int i0 = 0;
#pragma unroll
    for (int ee = 1; ee < 8; ee++) if (pr[ee] > pr[i0]) i0 = ee;
    int i1 = -1;
#pragma unroll
    for (int ee = 0; ee < 8; ee++) {
        if (ee == i0) continue;
        if (i1 < 0 || pr[ee] > pr[i1]) i1 = ee;
    }
    if (lane == 0) {
        top_idx[2 * t] = i0;
        top_idx[2 * t + 1] = i1;
        top_w[2 * t] = pr[i0];
        top_w[2 * t + 1] = pr[i1];
        atomicAdd(&counts[i0], 1);
        atomicAdd(&counts[i1], 1);
    }
}

__global__ void scan_kernel(const int* __restrict__ counts, int* __restrict__ offsets,
                            int* __restrict__ cursors) {
    if (threadIdx.x == 0) {
        int acc = 0;
        for (int e = 0; e < E_EXPERTS; e++) { offsets[e] = acc; acc += counts[e]; }
    }
    if (threadIdx.x < E_EXPERTS) cursors[threadIdx.x] = 0;
}

__global__ void scatter_kernel(const int* __restrict__ top_idx, const float* __restrict__ top_w,
                               const int* __restrict__ offsets, int* __restrict__ cursors,
                               int* __restrict__ perm, float* __restrict__ wgt) {
    int t = blockIdx.x * blockDim.x + threadIdx.x;
    if (t >= N_TOK) return;
#pragma unroll
    for (int sl = 0; sl < 2; sl++) {
        int ee = top_idx[2 * t + sl];
        int p = atomicAdd(&cursors[ee], 1);
        int s = offsets[ee] + p;
        perm[s] = t;
        wgt[s] = top_w[2 * t + sl];
    }
}

// ---------------- expert GEMMs (m97 structure: global_load_lds width-16) ----------------
// MODE 0: A = xb gathered via perm, B = W1T[e] [3072][768], epilogue GELU -> Hout bf16
// MODE 1: A = Hb contiguous slots,  B = W2T[e] [768][3072], epilogue weighted atomic -> Out f32
template <int MODE>
__global__ __launch_bounds__(256, 2) void moe_gemm_kernel(
    const ushort_t* __restrict__ A, const ushort_t* __restrict__ BT,
    const float* __restrict__ bias, const int* __restrict__ offsets,
    const int* __restrict__ counts, const int* __restrict__ perm,
    const float* __restrict__ wgt, ushort_t* __restrict__ Hout, float* __restrict__ Out) {
    constexpr int K = (MODE == 0) ? D_DIM : H_DIM;
    constexpr int N = (MODE == 0) ? H_DIM : D_DIM;

    const int e = blockIdx.z;
    const int ne = counts[e];
    const int m0 = blockIdx.y * 128;
    if (m0 >= ne) return;
    const int n0 = blockIdx.x * 128;
    const int base = offsets[e];

    const ushort_t* Bt = BT + (size_t)e * ((size_t)N * K);

    __shared__ alignas(16) ushort_t As[128 * 32];
    __shared__ alignas(16) ushort_t Bs[128 * 32];

    const int tid = threadIdx.x;
    const int lane = tid & 63;
    const int w = tid >> 6;
    const int wm = w >> 1, wn = w & 1;

    // each wave stages 2x1KB of A and 2x1KB of B per K-step via global_load_lds.
    // chunk index c = (w + 4*i)*64 + lane;  row = c>>2, col8 = (c&3)*8 (elements)
    const ushort_t* agl[2];
    const ushort_t* bgl[2];
    int lds_off[2];  // in ushorts, wave-uniform
#pragma unroll
    for (int i = 0; i < 2; i++) {
        int c = (w + 4 * i) * 64 + lane;
        int row = c >> 2;
        int col8 = (c & 3) * 8;
        int rclamp = min(m0 + row, ne - 1);
        size_t arow_g;
        if (MODE == 0)
            arow_g = (size_t)perm[base + rclamp] * K;
        else
            arow_g = (size_t)(base + rclamp) * K;
        agl[i] = A + arow_g + col8;
        bgl[i] = Bt + (size_t)(n0 + row) * K + col8;
        lds_off[i] = (w + 4 * i) * 512;  // 1KB per wave-load
    }

    f32x4 acc[4][4];
#pragma unroll
    for (int i = 0; i < 4; i++)
#pragma unroll
        for (int j = 0; j < 4; j++) acc[i][j] = (f32x4){0.f, 0.f, 0.f, 0.f};

    const int lr = lane & 15;
    const int lk = (lane >> 4) * 8;
    constexpr int KSTEPS = K / 32;

    for (int kt = 0; kt < KSTEPS; kt++) {
#pragma unroll
        for (int i = 0; i < 2; i++) {
            gload_lds16(agl[i] + kt * 32, &As[lds_off[i]]);
            gload_lds16(bgl[i] + kt * 32, &Bs[lds_off[i]]);
        }
        asm volatile("s_waitcnt vmcnt(0)" ::: "memory");
        __syncthreads();
        bf16x8 af[4], bfr[4];
#pragma unroll
        for (int f = 0; f < 4; f++) {
            af[f] = *(const bf16x8*)&As[(wm * 64 + f * 16 + lr) * 32 + lk];
            bfr[f] = *(const bf16x8*)&Bs[(wn * 64 + f * 16 + lr) * 32 + lk];
        }
#pragma unroll
        for (int i = 0; i < 4; i++)
#pragma unroll
            for (int j = 0; j < 4; j++)
                acc[i][j] = __builtin_amdgcn_mfma_f32_16x16x32_bf16(af[i], bfr[j], acc[i][j], 0, 0, 0);
        __syncthreads();
    }

    const int r0 = (lane >> 4) * 4;
#pragma unroll
    for (int fm = 0; fm < 4; fm++) {
#pragma unroll
        for (int fn = 0; fn < 4; fn++) {
            int cn = n0 + wn * 64 + fn * 16 + lr;
            float bi = bias[e * N + cn];
            f32x4 v = acc[fm][fn];
#pragma unroll
            for (int rg = 0; rg < 4; rg++) {
                int rm = m0 + wm * 64 + fm * 16 + r0 + rg;
                if (rm < ne) {
                    if (MODE == 0) {
                        float xv = v[rg] + bi;
                        float g = 0.5f * xv * (1.0f + erff(xv * 0.70710678118654752f));
                        Hout[(size_t)(base + rm) * H_DIM + cn] = f2bf(g);
                    } else {
                        int s = base + rm;
                        int tok = perm[s];
                        float wv = wgt[s];
                        unsafeAtomicAdd(&Out[(size_t)tok * D_DIM + cn], wv * (v[rg] + bi));
                    }
                }
            }
        }
    }
}

// ---------------- launch ----------------

extern "C" void kernel_launch(void* const* d_in, const int* in_sizes, int n_in,
                              void* d_out, int out_size, void* d_ws, size_t ws_size,
                              hipStream_t stream) {
    const float* x  = (const float*)d_in[0];
    const float* Wg = (const float*)d_in[1];
    const float* bg = (const float*)d_in[2];
    const float* W1 = (const float*)d_in[3];
    const float* b1 = (const float*)d_in[4];
    const float* W2 = (const float*)d_in[5];
    const float* b2 = (const float*)d_in[6];
    float* out = (float*)d_out;

    char* p = (char*)d_ws;
    ushort_t* xb  = (ushort_t*)p; p += (size_t)N_TOK * D_DIM * 2;
    ushort_t* W1T = (ushort_t*)p; p += (size_t)E_EXPERTS * H_DIM * D_DIM * 2;
    ushort_t* W2T = (ushort_t*)p; p += (size_t)E_EXPERTS * D_DIM * H_DIM * 2;
    ushort_t* Hb  = (ushort_t*)p; p += (size_t)SLOTS * H_DIM * 2;
    int*   top_idx = (int*)p;   p += (size_t)N_TOK * 2 * 4;
    float* top_w   = (float*)p; p += (size_t)N_TOK * 2 * 4;
    int*   perm    = (int*)p;   p += (size_t)SLOTS * 4;
    float* wgt     = (float*)p; p += (size_t)SLOTS * 4;
    int*   counts  = (int*)p;   p += 64;
    int*   offsets = (int*)p;   p += 64;
    int*   cursors = (int*)p;   p += 64;

    hipMemsetAsync(d_out, 0, (size_t)out_size * sizeof(float), stream);
    hipMemsetAsync(counts, 0, 64, stream);

    gate_kernel<<<N_TOK / 4, 256, 0, stream>>>(x, Wg, bg, xb, top_idx, top_w, counts);
    transpose_conv_kernel<<<dim3(H_DIM / 64, D_DIM / 64, E_EXPERTS), 256, 0, stream>>>(W1, W1T, D_DIM, H_DIM);
    transpose_conv_kernel<<<dim3(D_DIM / 64, H_DIM / 64, E_EXPERTS), 256, 0, stream>>>(W2, W2T, H_DIM, D_DIM);
    scan_kernel<<<1, 64, 0, stream>>>(counts, offsets, cursors);
    scatter_kernel<<<N_TOK / 256, 256, 0, stream>>>(top_idx, top_w, offsets, cursors, perm, wgt);
    moe_gemm_kernel<0><<<dim3(H_DIM / 128, 64, E_EXPERTS), 256, 0, stream>>>(
        xb, W1T, b1, offsets, counts, perm, wgt, Hb, nullptr);
    moe_gemm_kernel<1><<<dim3(D_DIM / 128, 64, E_EXPERTS), 256, 0, stream>>>(
        Hb, W2T, b2, offsets, counts, perm, wgt, nullptr, out);
}